// Round 4
// baseline (248.427 us; speedup 1.0000x reference)
//
#include <hip/hip_runtime.h>

#define EMB 64
#define DICT 512
#define HW 4096              // 64*64
#define NPTS (32 * HW)       // 131072
#define MOM 0.99f
#define OMOM 0.01f
#define EPSV 1e-5f

typedef float v2f __attribute__((ext_vector_type(2)));
typedef float v4f __attribute__((ext_vector_type(4)));

// ws layout (float offsets)
#define WS_COMMIT 0
#define WS_COUNTS 64                      // 512
#define WS_ESUM   1024                    // 64*512 = 32768 (esum[ch*512+j])
#define WS_ZERO_FLOATS 33792              // zero [0, 33792) each call
#define WS_EE     33792                   // 512
#define WS_N      34304                   // 1
#define WS_ET     34320                   // 64*512 = 32768 (ET[ch*512+j] = embed[j][ch])
#define WS_IDS    67088                   // 131072 ints (natural pixel order)

// ------------------------------------------------- prep: embed^T + ||e||^2
__global__ __launch_bounds__(256) void vq_prep(const float* __restrict__ embed,
                                               float* __restrict__ et,
                                               float* __restrict__ ee) {
    __shared__ float tl[64][65];
    int t = threadIdx.x;
    int j0 = blockIdx.x * 64;
    #pragma unroll
    for (int i = 0; i < 16; ++i) {
        int idx = t + i * 256;
        int jj = idx >> 6, ch = idx & 63;
        tl[jj][ch] = embed[(j0 + jj) * 64 + ch];
    }
    __syncthreads();
    #pragma unroll
    for (int i = 0; i < 16; ++i) {
        int idx = t + i * 256;
        int ch_o = idx >> 6, jj_o = idx & 63;
        et[ch_o * 512 + j0 + jj_o] = tl[jj_o][ch_o];
    }
    if (t < 64) {
        float s = 0.f;
        #pragma unroll
        for (int ch = 0; ch < 64; ++ch) s = fmaf(tl[t][ch], tl[t][ch], s);
        ee[j0 + t] = s;
    }
}

// ------------------------------------------------- argmax GEMM + fused epilogue
// block: 128 points x 128-code tiles, K=64 staged in LDS; thread: 8x8 tile.
// epilogue: quantized write + commit loss from Xs (no second pass over input).
__global__ __launch_bounds__(256, 2) void vq_argmax(
    const float* __restrict__ input, const float* __restrict__ et,
    const float* __restrict__ ee, const float* __restrict__ embed,
    float* __restrict__ out_q, float* __restrict__ out_ids,
    int* __restrict__ ws_ids, float* __restrict__ ws) {
    __shared__ float Xs[64 * 128];   // Xs[k][p]
    __shared__ float Es[64 * 128];   // Es[k][j2]
    __shared__ int   ids_s[128];
    __shared__ float cred[4];

    int t  = threadIdx.x;
    int tx = t & 15;                 // code octet
    int ty = t >> 4;                 // point octet
    int blk = blockIdx.x;
    int b   = blk >> 5;
    int h2  = blk & 31;              // 2 h-rows per block

    // stage X: Xs[ch][p] = input[b][ch][h2*128 + p], p in [0,128)
    const float* xg = input + (size_t)b * (EMB * HW) + h2 * 128;
    #pragma unroll
    for (int i = 0; i < 8; ++i) {
        int idx = t + i * 256;                 // float4 index, 2048 total
        int ch = idx >> 5, p4 = (idx & 31) << 2;
        v4f v = *(const v4f*)(xg + (size_t)ch * HW + p4);
        *(v4f*)&Xs[idx * 4] = v;
    }

    float best[8];
    int   bid[8];
    #pragma unroll
    for (int p = 0; p < 8; ++p) { best[p] = -3.0e38f; bid[p] = 0; }

    for (int jt = 0; jt < 4; ++jt) {
        int j0 = jt * 128;
        // stage E tile: Es[ch][j2] = et[ch*512 + j0 + j2]
        const float* eg = et + j0;
        #pragma unroll
        for (int i = 0; i < 8; ++i) {
            int idx = t + i * 256;
            int ch = idx >> 5, j24 = (idx & 31) << 2;
            v4f v = *(const v4f*)(eg + ch * 512 + j24);
            *(v4f*)&Es[idx * 4] = v;
        }
        __syncthreads();

        float ee8[8];
        #pragma unroll
        for (int jj = 0; jj < 8; ++jj) ee8[jj] = ee[j0 + (tx << 3) + jj];

        v2f acc[8][4];
        #pragma unroll
        for (int p = 0; p < 8; ++p)
            #pragma unroll
            for (int q = 0; q < 4; ++q) acc[p][q] = (v2f){0.f, 0.f};

        #pragma unroll 4
        for (int k = 0; k < 64; ++k) {
            v4f a0 = *(const v4f*)&Xs[k * 128 + (ty << 3)];
            v4f a1 = *(const v4f*)&Xs[k * 128 + (ty << 3) + 4];
            v4f b0 = *(const v4f*)&Es[k * 128 + (tx << 3)];
            v4f b1 = *(const v4f*)&Es[k * 128 + (tx << 3) + 4];
            v2f b2[4] = {{b0.x, b0.y}, {b0.z, b0.w}, {b1.x, b1.y}, {b1.z, b1.w}};
            float av[8] = {a0.x, a0.y, a0.z, a0.w, a1.x, a1.y, a1.z, a1.w};
            #pragma unroll
            for (int p = 0; p < 8; ++p) {
                v2f ap = {av[p], av[p]};
                #pragma unroll
                for (int q = 0; q < 4; ++q)
                    acc[p][q] = __builtin_elementwise_fma(ap, b2[q], acc[p][q]);
            }
        }

        // fold -||e||^2, running argmax (j ascending -> first-index tie-break)
        int jb = j0 + (tx << 3);
        #pragma unroll
        for (int p = 0; p < 8; ++p) {
            #pragma unroll
            for (int q = 0; q < 4; ++q) {
                float s0 = fmaf(2.f, acc[p][q].x, -ee8[2 * q]);
                if (s0 > best[p]) { best[p] = s0; bid[p] = jb + 2 * q; }
                float s1 = fmaf(2.f, acc[p][q].y, -ee8[2 * q + 1]);
                if (s1 > best[p]) { best[p] = s1; bid[p] = jb + 2 * q + 1; }
            }
        }
        __syncthreads();   // before overwriting Es next tile
    }

    // reduce over the 16 tx lanes sharing each point group
    #pragma unroll
    for (int p = 0; p < 8; ++p) {
        float bb = best[p];
        int   bi = bid[p];
        #pragma unroll
        for (int off = 8; off > 0; off >>= 1) {
            float ob = __shfl_xor(bb, off, 16);
            int   oi = __shfl_xor(bi, off, 16);
            if (ob > bb || (ob == bb && oi < bi)) { bb = ob; bi = oi; }
        }
        if (tx == 0) {
            int pl = (ty << 3) + p;            // local point 0..127
            int h = (h2 << 1) + (pl >> 6);
            int w = pl & 63;
            ids_s[pl] = bi;
            ws_ids[b * HW + h2 * 128 + pl] = bi;            // natural order
            out_ids[b * HW + w * 64 + h] = (float)bi;       // (b,w,h) quirk
        }
    }
    __syncthreads();

    // fused epilogue: quantized write + commit loss, straight from Xs.
    // thread -> (p = t&127, channel-quad half): 8 float4 embed gathers each.
    {
        int p   = t & 127;
        int cq0 = (t >> 7) * 8;                  // 0 or 8 (channel-quad base)
        int id  = ids_s[p];
        const v4f* e4g = (const v4f*)embed;      // embed[j][ch] rows, 16 quads
        float* qg = out_q + (size_t)b * (EMB * HW) + h2 * 128 + p;
        float cl = 0.f;
        #pragma unroll
        for (int c4 = 0; c4 < 8; ++c4) {
            int ch4 = cq0 + c4;
            v4f e = e4g[id * 16 + ch4];
            #pragma unroll
            for (int c = 0; c < 4; ++c) {
                int ch = ch4 * 4 + c;
                float x = Xs[ch * 128 + p];
                qg[(size_t)ch * HW] = e[c];
                float d = x - e[c];
                cl = fmaf(d, d, cl);
            }
        }
        #pragma unroll
        for (int off = 32; off > 0; off >>= 1) cl += __shfl_down(cl, off);
        if ((t & 63) == 0) cred[t >> 6] = cl;
    }
    __syncthreads();
    if (t == 0)
        unsafeAtomicAdd(&ws[WS_COMMIT], (cred[0] + cred[1]) + (cred[2] + cred[3]));
}

// ------------------------------------------------- stats: esum + counts
// block = (b, cg): 16 channels of one image; aggregate 4096 points in LDS.
__global__ __launch_bounds__(256) void vq_stats(
    const float* __restrict__ input, const int* __restrict__ ws_ids,
    float* __restrict__ ws) {
    __shared__ float es[DICT * 16];   // swizzled: (j, chl) at j*16 + (chl ^ (j&15))
    __shared__ int   ids_l[HW];
    __shared__ float cnt_s[DICT];

    int t = threadIdx.x;
    int bc = blockIdx.x;
    int b = bc >> 2, cg = bc & 3;

    for (int i = t; i < DICT * 16; i += 256) es[i] = 0.f;
    if (cg == 0) for (int i = t; i < DICT; i += 256) cnt_s[i] = 0.f;
    const int* idg = ws_ids + b * HW;
    for (int i = t; i < HW; i += 256) ids_l[i] = idg[i];
    __syncthreads();

    const float* xb = input + (size_t)b * (EMB * HW) + (size_t)(cg * 16) * HW;
    #pragma unroll 2
    for (int chl = 0; chl < 16; ++chl) {
        const float* xg = xb + (size_t)chl * HW;
        for (int i = t; i < HW; i += 256) {
            int id = ids_l[i];
            atomicAdd(&es[id * 16 + (chl ^ (id & 15))], xg[i]);
        }
    }
    if (cg == 0)
        for (int i = t; i < HW; i += 256) atomicAdd(&cnt_s[ids_l[i]], 1.f);
    __syncthreads();

    for (int i = t; i < DICT * 16; i += 256) {
        int j = i >> 4, chl = i & 15;
        float v = es[j * 16 + (chl ^ (j & 15))];
        if (v != 0.f)
            unsafeAtomicAdd(&ws[WS_ESUM + (cg * 16 + chl) * DICT + j], v);
    }
    if (cg == 0)
        for (int i = t; i < DICT; i += 256) {
            float c = cnt_s[i];
            if (c != 0.f) unsafeAtomicAdd(&ws[WS_COUNTS + i], c);
        }
}

// ---------------------------------------------------------------- finalize 1
__global__ __launch_bounds__(512) void vq_fin1(
    const float* __restrict__ cluster_size, float* __restrict__ ws,
    float* __restrict__ out_cs, float* __restrict__ out_loss) {
    __shared__ float red[DICT];
    int d = threadIdx.x;
    float ncs = cluster_size[d] * MOM + ws[WS_COUNTS + d] * OMOM;
    out_cs[d] = ncs;
    red[d] = ncs;
    __syncthreads();
    #pragma unroll
    for (int off = 256; off > 0; off >>= 1) {
        if (d < off) red[d] += red[d + off];
        __syncthreads();
    }
    if (d == 0) {
        ws[WS_N] = red[0];
        out_loss[0] = ws[WS_COMMIT] * (1.0f / (float)((size_t)NPTS * EMB));
    }
}

// ---------------------------------------------------------------- finalize 2
__global__ __launch_bounds__(256) void vq_fin2(
    const float* __restrict__ embed_avg, const float* __restrict__ cluster_size,
    const float* __restrict__ ws, float* __restrict__ out_embed,
    float* __restrict__ out_avg) {
    int idx = blockIdx.x * 256 + threadIdx.x;  // idx = ch*512 + d
    int ch = idx >> 9, d = idx & 511;
    float avg = embed_avg[idx] * MOM + ws[WS_ESUM + idx] * OMOM;
    out_avg[idx] = avg;
    float n = ws[WS_N];
    float ncs = cluster_size[d] * MOM + ws[WS_COUNTS + d] * OMOM;
    float cs = n * (ncs + EPSV) / (n + (float)DICT * EPSV);
    out_embed[d * EMB + ch] = avg / cs;
}

extern "C" void kernel_launch(void* const* d_in, const int* in_sizes, int n_in,
                              void* d_out, int out_size, void* d_ws, size_t ws_size,
                              hipStream_t stream) {
    const float* input        = (const float*)d_in[0];
    const float* embed        = (const float*)d_in[1];
    const float* cluster_size = (const float*)d_in[2];
    const float* embed_avg    = (const float*)d_in[3];

    float* out   = (float*)d_out;
    float* q     = out;                         // 8388608
    float* loss  = out + 8388608;               // 1
    float* ids   = out + 8388609;               // 131072
    float* oemb  = out + 8519681;               // 32768
    float* ocs   = out + 8552449;               // 512
    float* oavg  = out + 8552961;               // 32768
    float* ws    = (float*)d_ws;

    hipMemsetAsync(d_ws, 0, (size_t)WS_ZERO_FLOATS * sizeof(float), stream);
    vq_prep   <<<8, 256, 0, stream>>>(embed, ws + WS_ET, ws + WS_EE);
    vq_argmax <<<1024, 256, 0, stream>>>(input, ws + WS_ET, ws + WS_EE, embed,
                                         q, ids, (int*)(ws + WS_IDS), ws);
    vq_stats  <<<128, 256, 0, stream>>>(input, (const int*)(ws + WS_IDS), ws);
    vq_fin1   <<<1, 512, 0, stream>>>(cluster_size, ws, ocs, loss);
    vq_fin2   <<<128, 256, 0, stream>>>(embed_avg, cluster_size, ws, oemb, oavg);
}

// Round 5
// 187.432 us; speedup vs baseline: 1.3254x; 1.3254x over previous
//
#include <hip/hip_runtime.h>

#define EMB 64
#define DICT 512
#define HW 4096              // 64*64
#define NPTS (32 * HW)       // 131072
#define MOM 0.99f
#define OMOM 0.01f
#define EPSV 1e-5f

typedef float v2f __attribute__((ext_vector_type(2)));
typedef float v4f __attribute__((ext_vector_type(4)));

// ws layout (float offsets)
#define WS_COMMIT 0
#define WS_COUNTS 64                      // 512
#define WS_ESUM   1024                    // 64*512 = 32768 (esum[ch*512+j])
#define WS_ZERO_FLOATS 33792              // zero [0, 33792) each call
#define WS_EE     33792                   // 512
#define WS_N      34304                   // 1
#define WS_ET     34320                   // 64*512 = 32768 (ET[ch*512+j] = embed[j][ch])
#define WS_IDS    67088                   // 131072 ints (natural pixel order)

// ------------------------------------------------- prep: embed^T + ||e||^2
__global__ __launch_bounds__(256) void vq_prep(const float* __restrict__ embed,
                                               float* __restrict__ et,
                                               float* __restrict__ ee) {
    __shared__ float tl[64][65];
    int t = threadIdx.x;
    int j0 = blockIdx.x * 64;
    #pragma unroll
    for (int i = 0; i < 16; ++i) {
        int idx = t + i * 256;
        int jj = idx >> 6, ch = idx & 63;
        tl[jj][ch] = embed[(j0 + jj) * 64 + ch];
    }
    __syncthreads();
    #pragma unroll
    for (int i = 0; i < 16; ++i) {
        int idx = t + i * 256;
        int ch_o = idx >> 6, jj_o = idx & 63;
        et[ch_o * 512 + j0 + jj_o] = tl[jj_o][ch_o];
    }
    if (t < 64) {
        float s = 0.f;
        #pragma unroll
        for (int ch = 0; ch < 64; ++ch) s = fmaf(tl[t][ch], tl[t][ch], s);
        ee[j0 + t] = s;
    }
}

// ------------------------------------------------- argmax GEMM + fused epilogue
// block: 128 points x 128-code tiles, K=64 staged in LDS; thread: 8x8 tile.
// thread tx owns codes {4tx..4tx+3} and {64+4tx..64+4tx+3}: B-reads are
// 16B-stride quads -> 2-way bank aliasing (free), vs 32B-stride 4-way before.
__global__ __launch_bounds__(256, 2) void vq_argmax(
    const float* __restrict__ input, const float* __restrict__ et,
    const float* __restrict__ ee, const float* __restrict__ embed,
    float* __restrict__ out_q, float* __restrict__ out_ids,
    int* __restrict__ ws_ids, float* __restrict__ ws) {
    __shared__ float Xs[64 * 128];   // Xs[k][p]
    __shared__ float Es[64 * 128];   // Es[k][j2]
    __shared__ int   ids_s[128];
    __shared__ float cred[4];

    int t  = threadIdx.x;
    int tx = t & 15;                 // code owner lane
    int ty = t >> 4;                 // point octet
    int blk = blockIdx.x;
    int b   = blk >> 5;
    int h2  = blk & 31;              // 2 h-rows per block

    // stage X: Xs[ch][p] = input[b][ch][h2*128 + p], p in [0,128)
    const float* xg = input + (size_t)b * (EMB * HW) + h2 * 128;
    #pragma unroll
    for (int i = 0; i < 8; ++i) {
        int idx = t + i * 256;                 // float4 index, 2048 total
        int ch = idx >> 5, p4 = (idx & 31) << 2;
        v4f v = *(const v4f*)(xg + (size_t)ch * HW + p4);
        *(v4f*)&Xs[idx * 4] = v;
    }

    float best[8];
    int   bid[8];
    #pragma unroll
    for (int p = 0; p < 8; ++p) { best[p] = -3.0e38f; bid[p] = 0; }

    for (int jt = 0; jt < 4; ++jt) {
        int j0 = jt * 128;
        // stage E tile: Es[ch][j2] = et[ch*512 + j0 + j2]
        const float* eg = et + j0;
        #pragma unroll
        for (int i = 0; i < 8; ++i) {
            int idx = t + i * 256;
            int ch = idx >> 5, j24 = (idx & 31) << 2;
            v4f v = *(const v4f*)(eg + ch * 512 + j24);
            *(v4f*)&Es[idx * 4] = v;
        }
        __syncthreads();

        v4f eeA = *(const v4f*)&ee[j0 + (tx << 2)];
        v4f eeB = *(const v4f*)&ee[j0 + 64 + (tx << 2)];

        v2f acc[8][4];
        #pragma unroll
        for (int p = 0; p < 8; ++p)
            #pragma unroll
            for (int q = 0; q < 4; ++q) acc[p][q] = (v2f){0.f, 0.f};

        #pragma unroll 4
        for (int k = 0; k < 64; ++k) {
            v4f a0 = *(const v4f*)&Xs[k * 128 + (ty << 3)];
            v4f a1 = *(const v4f*)&Xs[k * 128 + (ty << 3) + 4];
            v4f b0 = *(const v4f*)&Es[k * 128 + (tx << 2)];        // codes 4tx..+3
            v4f b1 = *(const v4f*)&Es[k * 128 + 64 + (tx << 2)];   // codes 64+4tx..+3
            v2f b2[4] = {{b0.x, b0.y}, {b0.z, b0.w}, {b1.x, b1.y}, {b1.z, b1.w}};
            float av[8] = {a0.x, a0.y, a0.z, a0.w, a1.x, a1.y, a1.z, a1.w};
            #pragma unroll
            for (int p = 0; p < 8; ++p) {
                v2f ap = {av[p], av[p]};
                #pragma unroll
                for (int q = 0; q < 4; ++q)
                    acc[p][q] = __builtin_elementwise_fma(ap, b2[q], acc[p][q]);
            }
        }

        // fold -||e||^2, running argmax (per-thread codes ascending; jt ascending)
        int jA = j0 + (tx << 2);
        int jB = jA + 64;
        float eev[8] = {eeA.x, eeA.y, eeA.z, eeA.w, eeB.x, eeB.y, eeB.z, eeB.w};
        #pragma unroll
        for (int p = 0; p < 8; ++p) {
            #pragma unroll
            for (int q = 0; q < 4; ++q) {
                int jbase = (q < 2) ? (jA + 2 * q) : (jB + 2 * (q - 2));
                float s0 = fmaf(2.f, acc[p][q].x, -eev[2 * q]);
                if (s0 > best[p]) { best[p] = s0; bid[p] = jbase; }
                float s1 = fmaf(2.f, acc[p][q].y, -eev[2 * q + 1]);
                if (s1 > best[p]) { best[p] = s1; bid[p] = jbase + 1; }
            }
        }
        __syncthreads();   // before overwriting Es next tile
    }

    // reduce over the 16 tx lanes sharing each point group
    #pragma unroll
    for (int p = 0; p < 8; ++p) {
        float bb = best[p];
        int   bi = bid[p];
        #pragma unroll
        for (int off = 8; off > 0; off >>= 1) {
            float ob = __shfl_xor(bb, off, 16);
            int   oi = __shfl_xor(bi, off, 16);
            if (ob > bb || (ob == bb && oi < bi)) { bb = ob; bi = oi; }
        }
        if (tx == 0) {
            int pl = (ty << 3) + p;            // local point 0..127
            int h = (h2 << 1) + (pl >> 6);
            int w = pl & 63;
            ids_s[pl] = bi;
            ws_ids[b * HW + h2 * 128 + pl] = bi;            // natural order
            out_ids[b * HW + w * 64 + h] = (float)bi;       // (b,w,h) quirk
        }
    }
    __syncthreads();

    // fused epilogue: quantized write + commit loss, straight from Xs.
    {
        int p   = t & 127;
        int cq0 = (t >> 7) * 8;                  // 0 or 8 (channel-quad base)
        int id  = ids_s[p];
        const v4f* e4g = (const v4f*)embed;      // embed[j][ch] rows, 16 quads
        float* qg = out_q + (size_t)b * (EMB * HW) + h2 * 128 + p;
        float cl = 0.f;
        #pragma unroll
        for (int c4 = 0; c4 < 8; ++c4) {
            int ch4 = cq0 + c4;
            v4f e = e4g[id * 16 + ch4];
            #pragma unroll
            for (int c = 0; c < 4; ++c) {
                int ch = ch4 * 4 + c;
                float x = Xs[ch * 128 + p];
                qg[(size_t)ch * HW] = e[c];
                float d = x - e[c];
                cl = fmaf(d, d, cl);
            }
        }
        #pragma unroll
        for (int off = 32; off > 0; off >>= 1) cl += __shfl_down(cl, off);
        if ((t & 63) == 0) cred[t >> 6] = cl;
    }
    __syncthreads();
    if (t == 0)
        unsafeAtomicAdd(&ws[WS_COMMIT], (cred[0] + cred[1]) + (cred[2] + cred[3]));
}

// ------------------------------------------------- stats: esum + counts
// 512 blocks = (b, 16 groups of 4 channels). ids in registers (4x int4),
// fully unrolled independent loads; small LDS table -> high occupancy.
__global__ __launch_bounds__(256) void vq_stats(
    const float* __restrict__ input, const int* __restrict__ ws_ids,
    float* __restrict__ ws) {
    __shared__ float es[4 * 520];
    __shared__ float cnt_s[DICT];

    int t = threadIdx.x;
    int bc = blockIdx.x;
    int b = bc >> 4, cg = bc & 15;

    #pragma unroll
    for (int i = t; i < 4 * 520; i += 256) es[i] = 0.f;
    if (cg == 0)
        for (int i = t; i < DICT; i += 256) cnt_s[i] = 0.f;

    const int* idg = ws_ids + b * HW;
    int4 idv[4];
    #pragma unroll
    for (int it = 0; it < 4; ++it)
        idv[it] = *(const int4*)(idg + (t + it * 256) * 4);
    __syncthreads();

    #pragma unroll
    for (int chl = 0; chl < 4; ++chl) {
        const float* xg = input + (size_t)b * (EMB * HW) + (size_t)(cg * 4 + chl) * HW;
        float* esr = es + chl * 520;
        #pragma unroll
        for (int it = 0; it < 4; ++it) {
            v4f x = *(const v4f*)(xg + (t + it * 256) * 4);
            atomicAdd(&esr[idv[it].x], x.x);
            atomicAdd(&esr[idv[it].y], x.y);
            atomicAdd(&esr[idv[it].z], x.z);
            atomicAdd(&esr[idv[it].w], x.w);
        }
    }
    if (cg == 0) {
        #pragma unroll
        for (int it = 0; it < 4; ++it) {
            atomicAdd(&cnt_s[idv[it].x], 1.f);
            atomicAdd(&cnt_s[idv[it].y], 1.f);
            atomicAdd(&cnt_s[idv[it].z], 1.f);
            atomicAdd(&cnt_s[idv[it].w], 1.f);
        }
    }
    __syncthreads();

    #pragma unroll
    for (int i = t; i < 4 * DICT; i += 256) {
        int chl = i >> 9, j = i & 511;
        float v = es[chl * 520 + j];
        if (v != 0.f)
            unsafeAtomicAdd(&ws[WS_ESUM + (cg * 4 + chl) * DICT + j], v);
    }
    if (cg == 0)
        for (int i = t; i < DICT; i += 256) {
            float c = cnt_s[i];
            if (c != 0.f) unsafeAtomicAdd(&ws[WS_COUNTS + i], c);
        }
}

// ---------------------------------------------------------------- finalize 1
__global__ __launch_bounds__(512) void vq_fin1(
    const float* __restrict__ cluster_size, float* __restrict__ ws,
    float* __restrict__ out_cs, float* __restrict__ out_loss) {
    __shared__ float red[DICT];
    int d = threadIdx.x;
    float ncs = cluster_size[d] * MOM + ws[WS_COUNTS + d] * OMOM;
    out_cs[d] = ncs;
    red[d] = ncs;
    __syncthreads();
    #pragma unroll
    for (int off = 256; off > 0; off >>= 1) {
        if (d < off) red[d] += red[d + off];
        __syncthreads();
    }
    if (d == 0) {
        ws[WS_N] = red[0];
        out_loss[0] = ws[WS_COMMIT] * (1.0f / (float)((size_t)NPTS * EMB));
    }
}

// ---------------------------------------------------------------- finalize 2
__global__ __launch_bounds__(256) void vq_fin2(
    const float* __restrict__ embed_avg, const float* __restrict__ cluster_size,
    const float* __restrict__ ws, float* __restrict__ out_embed,
    float* __restrict__ out_avg) {
    int idx = blockIdx.x * 256 + threadIdx.x;  // idx = ch*512 + d
    int ch = idx >> 9, d = idx & 511;
    float avg = embed_avg[idx] * MOM + ws[WS_ESUM + idx] * OMOM;
    out_avg[idx] = avg;
    float n = ws[WS_N];
    float ncs = cluster_size[d] * MOM + ws[WS_COUNTS + d] * OMOM;
    float cs = n * (ncs + EPSV) / (n + (float)DICT * EPSV);
    out_embed[d * EMB + ch] = avg / cs;
}

extern "C" void kernel_launch(void* const* d_in, const int* in_sizes, int n_in,
                              void* d_out, int out_size, void* d_ws, size_t ws_size,
                              hipStream_t stream) {
    const float* input        = (const float*)d_in[0];
    const float* embed        = (const float*)d_in[1];
    const float* cluster_size = (const float*)d_in[2];
    const float* embed_avg    = (const float*)d_in[3];

    float* out   = (float*)d_out;
    float* q     = out;                         // 8388608
    float* loss  = out + 8388608;               // 1
    float* ids   = out + 8388609;               // 131072
    float* oemb  = out + 8519681;               // 32768
    float* ocs   = out + 8552449;               // 512
    float* oavg  = out + 8552961;               // 32768
    float* ws    = (float*)d_ws;

    hipMemsetAsync(d_ws, 0, (size_t)WS_ZERO_FLOATS * sizeof(float), stream);
    vq_prep   <<<8, 256, 0, stream>>>(embed, ws + WS_ET, ws + WS_EE);
    vq_argmax <<<1024, 256, 0, stream>>>(input, ws + WS_ET, ws + WS_EE, embed,
                                         q, ids, (int*)(ws + WS_IDS), ws);
    vq_stats  <<<512, 256, 0, stream>>>(input, (const int*)(ws + WS_IDS), ws);
    vq_fin1   <<<1, 512, 0, stream>>>(cluster_size, ws, ocs, loss);
    vq_fin2   <<<128, 256, 0, stream>>>(embed_avg, cluster_size, ws, oemb, oavg);
}

// Round 7
// 185.056 us; speedup vs baseline: 1.3424x; 1.0128x over previous
//
#include <hip/hip_runtime.h>

#define EMB 64
#define DICT 512
#define HW 4096              // 64*64
#define NPTS (32 * HW)       // 131072
#define MOM 0.99f
#define OMOM 0.01f
#define EPSV 1e-5f

typedef float v2f __attribute__((ext_vector_type(2)));
typedef float v4f __attribute__((ext_vector_type(4)));

// ws layout (float offsets)
#define WS_COMMIT 0
#define WS_COUNTS 64                      // 512
#define WS_ESUM   1024                    // 64*512 = 32768 (esum[ch*512+j])
#define WS_ZERO_FLOATS 33792              // zero [0, 33792) each call
#define WS_EE     33792                   // 512
#define WS_N      34304                   // 1
#define WS_ET     34320                   // 64*512 = 32768 (ET[ch*512+j] = embed[j][ch])
#define WS_IDS    67088                   // 131072 ints (natural pixel order)

// VOP3P: all sources are VGPR pairs. Broadcast one half of X to both lanes:
// acc.lo += X.h * B.lo ; acc.hi += X.h * B.hi   (h = lo or hi via op_sel)
#define PKFMA_LO(ACC, X2, B) \
    asm("v_pk_fma_f32 %0, %1, %2, %0 op_sel:[0,0,0] op_sel_hi:[0,1,1]" \
        : "+v"(ACC) : "v"(X2), "v"(B))
#define PKFMA_HI(ACC, X2, B) \
    asm("v_pk_fma_f32 %0, %1, %2, %0 op_sel:[1,0,0] op_sel_hi:[1,1,1]" \
        : "+v"(ACC) : "v"(X2), "v"(B))

// ------------------------------------------------- prep: embed^T + ||e||^2
__global__ __launch_bounds__(256) void vq_prep(const float* __restrict__ embed,
                                               float* __restrict__ et,
                                               float* __restrict__ ee) {
    __shared__ float tl[64][65];
    int t = threadIdx.x;
    int j0 = blockIdx.x * 64;
    #pragma unroll
    for (int i = 0; i < 16; ++i) {
        int idx = t + i * 256;
        int jj = idx >> 6, ch = idx & 63;
        tl[jj][ch] = embed[(j0 + jj) * 64 + ch];
    }
    __syncthreads();
    #pragma unroll
    for (int i = 0; i < 16; ++i) {
        int idx = t + i * 256;
        int ch_o = idx >> 6, jj_o = idx & 63;
        et[ch_o * 512 + j0 + jj_o] = tl[jj_o][ch_o];
    }
    if (t < 64) {
        float s = 0.f;
        #pragma unroll
        for (int ch = 0; ch < 64; ++ch) s = fmaf(tl[t][ch], tl[t][ch], s);
        ee[j0 + t] = s;
    }
}

// ------------------------------------------------- argmax GEMM + fused epilogue
// block: 128 points x 128-code tiles, K=64 staged in LDS; thread: 8x8 tile.
// inner loop: explicit v_pk_fma_f32, op_sel broadcast from A-pair halves.
__global__ __launch_bounds__(256, 2) void vq_argmax(
    const float* __restrict__ input, const float* __restrict__ et,
    const float* __restrict__ ee, const float* __restrict__ embed,
    float* __restrict__ out_q, float* __restrict__ out_ids,
    int* __restrict__ ws_ids, float* __restrict__ ws) {
    __shared__ float Xs[64 * 128];   // Xs[k][p]
    __shared__ float Es[64 * 128];   // Es[k][j2]
    __shared__ int   ids_s[128];
    __shared__ float cred[4];

    int t  = threadIdx.x;
    int tx = t & 15;                 // code owner lane
    int ty = t >> 4;                 // point octet
    int blk = blockIdx.x;
    int b   = blk >> 5;
    int h2  = blk & 31;              // 2 h-rows per block

    // stage X: Xs[ch][p] = input[b][ch][h2*128 + p], p in [0,128)
    const float* xg = input + (size_t)b * (EMB * HW) + h2 * 128;
    #pragma unroll
    for (int i = 0; i < 8; ++i) {
        int idx = t + i * 256;                 // float4 index, 2048 total
        int ch = idx >> 5, p4 = (idx & 31) << 2;
        v4f v = *(const v4f*)(xg + (size_t)ch * HW + p4);
        *(v4f*)&Xs[idx * 4] = v;
    }

    float best[8];
    int   bid[8];
    #pragma unroll
    for (int p = 0; p < 8; ++p) { best[p] = -3.0e38f; bid[p] = 0; }

    for (int jt = 0; jt < 4; ++jt) {
        int j0 = jt * 128;
        // stage E tile: Es[ch][j2] = et[ch*512 + j0 + j2]
        const float* eg = et + j0;
        #pragma unroll
        for (int i = 0; i < 8; ++i) {
            int idx = t + i * 256;
            int ch = idx >> 5, j24 = (idx & 31) << 2;
            v4f v = *(const v4f*)(eg + ch * 512 + j24);
            *(v4f*)&Es[idx * 4] = v;
        }
        __syncthreads();

        v4f eeA = *(const v4f*)&ee[j0 + (tx << 2)];
        v4f eeB = *(const v4f*)&ee[j0 + 64 + (tx << 2)];

        v2f acc[8][4];
        #pragma unroll
        for (int p = 0; p < 8; ++p)
            #pragma unroll
            for (int q = 0; q < 4; ++q) acc[p][q] = (v2f){0.f, 0.f};

        #pragma unroll 4
        for (int k = 0; k < 64; ++k) {
            v4f a0 = *(const v4f*)&Xs[k * 128 + (ty << 3)];
            v4f a1 = *(const v4f*)&Xs[k * 128 + (ty << 3) + 4];
            const v2f* bB = (const v2f*)&Es[k * 128];
            v2f b2[4];
            b2[0] = bB[(tx << 1)];          // codes 4tx, 4tx+1
            b2[1] = bB[(tx << 1) + 1];      // codes 4tx+2, 4tx+3
            b2[2] = bB[32 + (tx << 1)];     // codes 64+4tx, +1
            b2[3] = bB[32 + (tx << 1) + 1]; // codes 64+4tx+2, +3
            v2f xa[4] = {{a0.x, a0.y}, {a0.z, a0.w}, {a1.x, a1.y}, {a1.z, a1.w}};
            #pragma unroll
            for (int ph = 0; ph < 4; ++ph) {
                #pragma unroll
                for (int q = 0; q < 4; ++q)
                    PKFMA_LO(acc[2 * ph][q], xa[ph], b2[q]);
                #pragma unroll
                for (int q = 0; q < 4; ++q)
                    PKFMA_HI(acc[2 * ph + 1][q], xa[ph], b2[q]);
            }
        }

        // fold -||e||^2, running argmax (per-thread codes ascending; jt ascending)
        int jA = j0 + (tx << 2);
        int jB = jA + 64;
        float eev[8] = {eeA.x, eeA.y, eeA.z, eeA.w, eeB.x, eeB.y, eeB.z, eeB.w};
        #pragma unroll
        for (int p = 0; p < 8; ++p) {
            #pragma unroll
            for (int q = 0; q < 4; ++q) {
                int jbase = (q < 2) ? (jA + 2 * q) : (jB + 2 * (q - 2));
                float s0 = fmaf(2.f, acc[p][q].x, -eev[2 * q]);
                if (s0 > best[p]) { best[p] = s0; bid[p] = jbase; }
                float s1 = fmaf(2.f, acc[p][q].y, -eev[2 * q + 1]);
                if (s1 > best[p]) { best[p] = s1; bid[p] = jbase + 1; }
            }
        }
        __syncthreads();   // before overwriting Es next tile
    }

    // reduce over the 16 tx lanes sharing each point group
    #pragma unroll
    for (int p = 0; p < 8; ++p) {
        float bb = best[p];
        int   bi = bid[p];
        #pragma unroll
        for (int off = 8; off > 0; off >>= 1) {
            float ob = __shfl_xor(bb, off, 16);
            int   oi = __shfl_xor(bi, off, 16);
            if (ob > bb || (ob == bb && oi < bi)) { bb = ob; bi = oi; }
        }
        if (tx == 0) {
            int pl = (ty << 3) + p;            // local point 0..127
            int h = (h2 << 1) + (pl >> 6);
            int w = pl & 63;
            ids_s[pl] = bi;
            ws_ids[b * HW + h2 * 128 + pl] = bi;            // natural order
            out_ids[b * HW + w * 64 + h] = (float)bi;       // (b,w,h) quirk
        }
    }
    __syncthreads();

    // fused epilogue: quantized write + commit loss, straight from Xs.
    {
        int p   = t & 127;
        int cq0 = (t >> 7) * 8;                  // 0 or 8 (channel-quad base)
        int id  = ids_s[p];
        const v4f* e4g = (const v4f*)embed;      // embed[j][ch] rows, 16 quads
        float* qg = out_q + (size_t)b * (EMB * HW) + h2 * 128 + p;
        float cl = 0.f;
        #pragma unroll
        for (int c4 = 0; c4 < 8; ++c4) {
            int ch4 = cq0 + c4;
            v4f e = e4g[id * 16 + ch4];
            #pragma unroll
            for (int c = 0; c < 4; ++c) {
                int ch = ch4 * 4 + c;
                float x = Xs[ch * 128 + p];
                qg[(size_t)ch * HW] = e[c];
                float d = x - e[c];
                cl = fmaf(d, d, cl);
            }
        }
        #pragma unroll
        for (int off = 32; off > 0; off >>= 1) cl += __shfl_down(cl, off);
        if ((t & 63) == 0) cred[t >> 6] = cl;
    }
    __syncthreads();
    if (t == 0)
        unsafeAtomicAdd(&ws[WS_COMMIT], (cred[0] + cred[1]) + (cred[2] + cred[3]));
}

// ------------------------------------------------- stats: esum + counts
// 512 blocks = (b, 16 groups of 4 channels). ids in registers (4x int4),
// fully unrolled independent loads; small LDS table -> high occupancy.
__global__ __launch_bounds__(256) void vq_stats(
    const float* __restrict__ input, const int* __restrict__ ws_ids,
    float* __restrict__ ws) {
    __shared__ float es[4 * 520];
    __shared__ float cnt_s[DICT];

    int t = threadIdx.x;
    int bc = blockIdx.x;
    int b = bc >> 4, cg = bc & 15;

    #pragma unroll
    for (int i = t; i < 4 * 520; i += 256) es[i] = 0.f;
    if (cg == 0)
        for (int i = t; i < DICT; i += 256) cnt_s[i] = 0.f;

    const int* idg = ws_ids + b * HW;
    int4 idv[4];
    #pragma unroll
    for (int it = 0; it < 4; ++it)
        idv[it] = *(const int4*)(idg + (t + it * 256) * 4);
    __syncthreads();

    #pragma unroll
    for (int chl = 0; chl < 4; ++chl) {
        const float* xg = input + (size_t)b * (EMB * HW) + (size_t)(cg * 4 + chl) * HW;
        float* esr = es + chl * 520;
        #pragma unroll
        for (int it = 0; it < 4; ++it) {
            v4f x = *(const v4f*)(xg + (t + it * 256) * 4);
            atomicAdd(&esr[idv[it].x], x.x);
            atomicAdd(&esr[idv[it].y], x.y);
            atomicAdd(&esr[idv[it].z], x.z);
            atomicAdd(&esr[idv[it].w], x.w);
        }
    }
    if (cg == 0) {
        #pragma unroll
        for (int it = 0; it < 4; ++it) {
            atomicAdd(&cnt_s[idv[it].x], 1.f);
            atomicAdd(&cnt_s[idv[it].y], 1.f);
            atomicAdd(&cnt_s[idv[it].z], 1.f);
            atomicAdd(&cnt_s[idv[it].w], 1.f);
        }
    }
    __syncthreads();

    #pragma unroll
    for (int i = t; i < 4 * DICT; i += 256) {
        int chl = i >> 9, j = i & 511;
        float v = es[chl * 520 + j];
        if (v != 0.f)
            unsafeAtomicAdd(&ws[WS_ESUM + (cg * 4 + chl) * DICT + j], v);
    }
    if (cg == 0)
        for (int i = t; i < DICT; i += 256) {
            float c = cnt_s[i];
            if (c != 0.f) unsafeAtomicAdd(&ws[WS_COUNTS + i], c);
        }
}

// ---------------------------------------------------------------- finalize 1
__global__ __launch_bounds__(512) void vq_fin1(
    const float* __restrict__ cluster_size, float* __restrict__ ws,
    float* __restrict__ out_cs, float* __restrict__ out_loss) {
    __shared__ float red[DICT];
    int d = threadIdx.x;
    float ncs = cluster_size[d] * MOM + ws[WS_COUNTS + d] * OMOM;
    out_cs[d] = ncs;
    red[d] = ncs;
    __syncthreads();
    #pragma unroll
    for (int off = 256; off > 0; off >>= 1) {
        if (d < off) red[d] += red[d + off];
        __syncthreads();
    }
    if (d == 0) {
        ws[WS_N] = red[0];
        out_loss[0] = ws[WS_COMMIT] * (1.0f / (float)((size_t)NPTS * EMB));
    }
}

// ---------------------------------------------------------------- finalize 2
__global__ __launch_bounds__(256) void vq_fin2(
    const float* __restrict__ embed_avg, const float* __restrict__ cluster_size,
    const float* __restrict__ ws, float* __restrict__ out_embed,
    float* __restrict__ out_avg) {
    int idx = blockIdx.x * 256 + threadIdx.x;  // idx = ch*512 + d
    int ch = idx >> 9, d = idx & 511;
    float avg = embed_avg[idx] * MOM + ws[WS_ESUM + idx] * OMOM;
    out_avg[idx] = avg;
    float n = ws[WS_N];
    float ncs = cluster_size[d] * MOM + ws[WS_COUNTS + d] * OMOM;
    float cs = n * (ncs + EPSV) / (n + (float)DICT * EPSV);
    out_embed[d * EMB + ch] = avg / cs;
}

extern "C" void kernel_launch(void* const* d_in, const int* in_sizes, int n_in,
                              void* d_out, int out_size, void* d_ws, size_t ws_size,
                              hipStream_t stream) {
    const float* input        = (const float*)d_in[0];
    const float* embed        = (const float*)d_in[1];
    const float* cluster_size = (const float*)d_in[2];
    const float* embed_avg    = (const float*)d_in[3];

    float* out   = (float*)d_out;
    float* q     = out;                         // 8388608
    float* loss  = out + 8388608;               // 1
    float* ids   = out + 8388609;               // 131072
    float* oemb  = out + 8519681;               // 32768
    float* ocs   = out + 8552449;               // 512
    float* oavg  = out + 8552961;               // 32768
    float* ws    = (float*)d_ws;

    hipMemsetAsync(d_ws, 0, (size_t)WS_ZERO_FLOATS * sizeof(float), stream);
    vq_prep   <<<8, 256, 0, stream>>>(embed, ws + WS_ET, ws + WS_EE);
    vq_argmax <<<1024, 256, 0, stream>>>(input, ws + WS_ET, ws + WS_EE, embed,
                                         q, ids, (int*)(ws + WS_IDS), ws);
    vq_stats  <<<512, 256, 0, stream>>>(input, (const int*)(ws + WS_IDS), ws);
    vq_fin1   <<<1, 512, 0, stream>>>(cluster_size, ws, ocs, loss);
    vq_fin2   <<<128, 256, 0, stream>>>(embed_avg, cluster_size, ws, oemb, oavg);
}

// Round 8
// 149.877 us; speedup vs baseline: 1.6575x; 1.2347x over previous
//
#include <hip/hip_runtime.h>

#define EMB 64
#define DICT 512
#define HW 4096              // 64*64
#define NPTS (32 * HW)       // 131072
#define MOM 0.99f
#define OMOM 0.01f
#define EPSV 1e-5f

typedef float v4f __attribute__((ext_vector_type(4)));
typedef unsigned int uint;
typedef uint uint4v __attribute__((ext_vector_type(4)));
typedef short short8 __attribute__((ext_vector_type(8)));
typedef __bf16 bf16x8 __attribute__((ext_vector_type(8)));
typedef float f32x4 __attribute__((ext_vector_type(4)));

// ws layout (dword offsets)
#define WS_COMMIT 0
#define WS_COUNTS 64                      // 512
#define WS_ESUM   1024                    // 64*512
#define WS_ZERO_FLOATS 33792              // zero [0, 33792) each call
#define WS_EE     33792                   // 512 (fp32 ||e||^2)
#define WS_N      34304                   // 1
#define WS_EHG    34320                   // 4 tiles * 4160 = 16640 (packed bf16-hi E)
#define WS_ELG    50960                   // 16640 (packed bf16-lo E)
#define WS_IDS    67600                   // 131072 ints (natural pixel order)

#define PS 520      // plane stride in dwords: 130 rows x 4 dwords
#define TB 4160     // tile blob: 8 planes (kh*4+g)

__device__ __forceinline__ uint bf16rne(float x) {
    uint u = __float_as_uint(x);
    return (u + 0x7fffu + ((u >> 16) & 1u)) >> 16;
}

__device__ __forceinline__ bf16x8 ldfrag(const uint* s, int idx) {
    return __builtin_bit_cast(bf16x8, *(const short8*)(s + idx));
}

// ------------------------------------------------- prep: pack E hi/lo + ||e||^2
// 4 blocks x 256; block = one 128-code tile. Packed layout (per tile):
// dword[(kh*4+g)*520 + j_local*4 + v] = bf16(e[ch=2*(kh*16+g*4+v... )]) pair,
// where c2 = kh*16+g*4+v, channels (2*c2, 2*c2+1) packed lo|hi<<16.
__global__ __launch_bounds__(256) void vq_prep(const float* __restrict__ embed,
                                               uint* __restrict__ ehg,
                                               uint* __restrict__ elg,
                                               float* __restrict__ ee) {
    __shared__ float pn[256];
    int t = threadIdx.x;
    int tt = blockIdx.x;
    int jl = t & 127;
    int j = tt * 128 + jl;
    int half = t >> 7;
    float nrm = 0.f;
    #pragma unroll
    for (int i = 0; i < 16; ++i) {
        int c2 = half * 16 + i;
        float x0 = embed[j * 64 + 2 * c2];
        float x1 = embed[j * 64 + 2 * c2 + 1];
        nrm = fmaf(x0, x0, nrm);
        nrm = fmaf(x1, x1, nrm);
        uint h0 = bf16rne(x0), h1 = bf16rne(x1);
        float hf0 = __uint_as_float(h0 << 16), hf1 = __uint_as_float(h1 << 16);
        uint l0 = bf16rne(x0 - hf0), l1 = bf16rne(x1 - hf1);
        int plane = (c2 >> 4) * 4 + ((c2 >> 2) & 3);
        int idx = tt * TB + plane * PS + jl * 4 + (c2 & 3);
        ehg[idx] = h0 | (h1 << 16);
        elg[idx] = l0 | (l1 << 16);
    }
    pn[t] = nrm;
    __syncthreads();
    if (t < 128) ee[tt * 128 + t] = pn[t] + pn[t + 128];
}

// ------------------------------------------------- MFMA argmax + exact rescore
// block: 128 points, 4 waves (wave w = points 32w..32w+31, 2 m-tiles of 16).
// 3-term bf16-split MFMA over 4 code-tiles of 128; per-lane top-2 + 16-lane
// top-2 merge; fp32 rescore of both candidates decides; fused q/ids/commit.
__global__ __launch_bounds__(256, 2) void vq_argmax(
    const float* __restrict__ input, const uint* __restrict__ ehg,
    const uint* __restrict__ elg, const float* __restrict__ ee,
    const float* __restrict__ embed, float* __restrict__ out_q,
    float* __restrict__ out_ids, int* __restrict__ ws_ids,
    float* __restrict__ ws) {
    __shared__ uint sXh[TB], sXl[TB], sEh[TB], sEl[TB];
    __shared__ float sEE[512];
    __shared__ int sCand[256];
    __shared__ float sRes[256];
    __shared__ float cred[4];

    int t = threadIdx.x;
    int blk = blockIdx.x;
    int b = blk >> 5, h2 = blk & 31;

    // ---- stage X as packed hi/lo bf16 planes (conflict-free writes) ----
    {
        int p = t & 127;
        const float* xg = input + (size_t)b * (EMB * HW) + h2 * 128 + p;
        #pragma unroll
        for (int i = 0; i < 16; ++i) {
            int c2 = (t >> 7) * 16 + i;
            float x0 = xg[(size_t)(2 * c2) * HW];
            float x1 = xg[(size_t)(2 * c2 + 1) * HW];
            uint h0 = bf16rne(x0), h1 = bf16rne(x1);
            float hf0 = __uint_as_float(h0 << 16), hf1 = __uint_as_float(h1 << 16);
            uint l0 = bf16rne(x0 - hf0), l1 = bf16rne(x1 - hf1);
            int plane = (c2 >> 4) * 4 + ((c2 >> 2) & 3);
            int idx = plane * PS + p * 4 + (c2 & 3);
            sXh[idx] = h0 | (h1 << 16);
            sXl[idx] = l0 | (l1 << 16);
        }
        sEE[t] = ee[t];
        sEE[t + 256] = ee[t + 256];
        for (int i = t; i < TB / 4; i += 256) {
            *(uint4v*)&sEh[i * 4] = *(const uint4v*)&ehg[i * 4];
            *(uint4v*)&sEl[i * 4] = *(const uint4v*)&elg[i * 4];
        }
    }
    __syncthreads();

    int l = t & 63, wv = t >> 6;
    int g = l >> 4, col = l & 15;

    // A fragments (X) — constant across all 4 code-tiles
    bf16x8 Ah[2][2], Al[2][2];     // [mt][kh]
    #pragma unroll
    for (int mt = 0; mt < 2; ++mt)
        #pragma unroll
        for (int kh = 0; kh < 2; ++kh) {
            int row = wv * 32 + mt * 16 + col;
            int idx = (kh * 4 + g) * PS + row * 4;
            Ah[mt][kh] = ldfrag(sXh, idx);
            Al[mt][kh] = ldfrag(sXl, idx);
        }

    // per-lane top-2 per (mt, r) slot
    float tb1[2][4], tb2[2][4];
    int ti1[2][4], ti2[2][4];
    #pragma unroll
    for (int mt = 0; mt < 2; ++mt)
        #pragma unroll
        for (int r = 0; r < 4; ++r) {
            tb1[mt][r] = -3.0e38f; tb2[mt][r] = -3.0e38f;
            ti1[mt][r] = 0; ti2[mt][r] = 0;
        }

    for (int jt = 0; jt < 4; ++jt) {
        f32x4 acc[2][8];
        #pragma unroll
        for (int nt = 0; nt < 8; ++nt) {
            float e2 = -0.5f * sEE[jt * 128 + nt * 16 + col];
            f32x4 ini = {e2, e2, e2, e2};
            acc[0][nt] = ini;
            acc[1][nt] = ini;
        }
        #pragma unroll
        for (int nt = 0; nt < 8; ++nt) {
            int i0 = (0 * 4 + g) * PS + (nt * 16 + col) * 4;
            int i1x = (1 * 4 + g) * PS + (nt * 16 + col) * 4;
            bf16x8 Bh0 = ldfrag(sEh, i0), Bl0 = ldfrag(sEl, i0);
            bf16x8 Bh1 = ldfrag(sEh, i1x), Bl1 = ldfrag(sEl, i1x);
            #pragma unroll
            for (int mt = 0; mt < 2; ++mt) {
                f32x4 a = acc[mt][nt];
                a = __builtin_amdgcn_mfma_f32_16x16x32_bf16(Ah[mt][0], Bh0, a, 0, 0, 0);
                a = __builtin_amdgcn_mfma_f32_16x16x32_bf16(Ah[mt][0], Bl0, a, 0, 0, 0);
                a = __builtin_amdgcn_mfma_f32_16x16x32_bf16(Al[mt][0], Bh0, a, 0, 0, 0);
                a = __builtin_amdgcn_mfma_f32_16x16x32_bf16(Ah[mt][1], Bh1, a, 0, 0, 0);
                a = __builtin_amdgcn_mfma_f32_16x16x32_bf16(Ah[mt][1], Bl1, a, 0, 0, 0);
                a = __builtin_amdgcn_mfma_f32_16x16x32_bf16(Al[mt][1], Bh1, a, 0, 0, 0);
                acc[mt][nt] = a;
            }
        }
        // running top-2 (codes ascending -> first-index tie-break)
        #pragma unroll
        for (int mt = 0; mt < 2; ++mt)
            #pragma unroll
            for (int nt = 0; nt < 8; ++nt) {
                int jc = jt * 128 + nt * 16 + col;
                #pragma unroll
                for (int r = 0; r < 4; ++r) {
                    float s = acc[mt][nt][r];
                    if (s > tb1[mt][r]) {
                        tb2[mt][r] = tb1[mt][r]; ti2[mt][r] = ti1[mt][r];
                        tb1[mt][r] = s; ti1[mt][r] = jc;
                    } else if (s > tb2[mt][r]) {
                        tb2[mt][r] = s; ti2[mt][r] = jc;
                    }
                }
            }
        if (jt < 3) {
            __syncthreads();
            const uint* eh = ehg + (jt + 1) * TB;
            const uint* el = elg + (jt + 1) * TB;
            for (int i = t; i < TB / 4; i += 256) {
                *(uint4v*)&sEh[i * 4] = *(const uint4v*)&eh[i * 4];
                *(uint4v*)&sEl[i * 4] = *(const uint4v*)&el[i * 4];
            }
            __syncthreads();
        }
    }

    // 16-lane top-2 merge per point; lane col==0 publishes candidates
    #pragma unroll
    for (int mt = 0; mt < 2; ++mt)
        #pragma unroll
        for (int r = 0; r < 4; ++r) {
            float a1 = tb1[mt][r], a2 = tb2[mt][r];
            int j1 = ti1[mt][r], j2 = ti2[mt][r];
            #pragma unroll
            for (int off = 8; off > 0; off >>= 1) {
                float c1 = __shfl_xor(a1, off, 16); int k1 = __shfl_xor(j1, off, 16);
                float c2v = __shfl_xor(a2, off, 16); int k2 = __shfl_xor(j2, off, 16);
                bool af = (a1 > c1) || (a1 == c1 && j1 < k1);
                float n1 = af ? a1 : c1; int nj1 = af ? j1 : k1;
                float lx = af ? c1 : a1; int lj = af ? k1 : j1;   // loser of tops
                float wx = af ? a2 : c2v; int wj = af ? j2 : k2;  // winner's 2nd
                bool wf = (wx > lx) || (wx == lx && wj < lj);
                a1 = n1; j1 = nj1;
                a2 = wf ? wx : lx; j2 = wf ? wj : lj;
            }
            if (col == 0) {
                int p = wv * 32 + mt * 16 + g * 4 + r;
                sCand[p * 2] = j1;
                sCand[p * 2 + 1] = j2;
            }
        }
    __syncthreads();

    // ---- exact fp32 rescore of both candidates (2 threads per point) ----
    int p = t & 127, wc = t >> 7;
    int c = sCand[p * 2 + wc];
    const v4f* erow = (const v4f*)(embed + c * 64);
    float dot = 0.f;
    #pragma unroll
    for (int plane = 0; plane < 8; ++plane) {
        uint4v xh = *(const uint4v*)&sXh[plane * PS + p * 4];
        uint4v xl = *(const uint4v*)&sXl[plane * PS + p * 4];
        v4f e0 = erow[plane * 2];
        v4f e1 = erow[plane * 2 + 1];
        #pragma unroll
        for (int v = 0; v < 4; ++v) {
            float xe = __uint_as_float(xh[v] << 16) + __uint_as_float(xl[v] << 16);
            float xo = __uint_as_float(xh[v] & 0xffff0000u) + __uint_as_float(xl[v] & 0xffff0000u);
            float ev_ = (v < 2) ? e0[2 * (v & 1)] : e1[2 * (v & 1)];
            float ov_ = (v < 2) ? e0[2 * (v & 1) + 1] : e1[2 * (v & 1) + 1];
            dot = fmaf(xe, ev_, dot);
            dot = fmaf(xo, ov_, dot);
        }
    }
    float sx = fmaf(2.f, dot, -sEE[c]);
    sRes[t] = sx;
    __syncthreads();
    float so = sRes[t ^ 128];
    int co = sCand[p * 2 + (1 - wc)];
    bool win = (sx > so) || (sx == so && c < co);

    // winner: ids + quantized + commit contribution
    float cl = 0.f;
    if (win) {
        int h = (h2 << 1) + (p >> 6), w = p & 63;
        ws_ids[b * HW + h2 * 128 + p] = c;                 // natural order
        out_ids[b * HW + w * 64 + h] = (float)c;           // (b,w,h) quirk
        float* qg = out_q + (size_t)b * (EMB * HW) + h2 * 128 + p;
        #pragma unroll
        for (int plane = 0; plane < 8; ++plane) {
            uint4v xh = *(const uint4v*)&sXh[plane * PS + p * 4];
            uint4v xl = *(const uint4v*)&sXl[plane * PS + p * 4];
            v4f e0 = erow[plane * 2];
            v4f e1 = erow[plane * 2 + 1];
            #pragma unroll
            for (int v = 0; v < 4; ++v) {
                float xe = __uint_as_float(xh[v] << 16) + __uint_as_float(xl[v] << 16);
                float xo = __uint_as_float(xh[v] & 0xffff0000u) + __uint_as_float(xl[v] & 0xffff0000u);
                float ev_ = (v < 2) ? e0[2 * (v & 1)] : e1[2 * (v & 1)];
                float ov_ = (v < 2) ? e0[2 * (v & 1) + 1] : e1[2 * (v & 1) + 1];
                int ch = plane * 8 + 2 * v;
                qg[(size_t)ch * HW] = ev_;
                qg[(size_t)(ch + 1) * HW] = ov_;
                float d0 = xe - ev_, d1 = xo - ov_;
                cl = fmaf(d0, d0, cl);
                cl = fmaf(d1, d1, cl);
            }
        }
    }
    #pragma unroll
    for (int off = 32; off > 0; off >>= 1) cl += __shfl_down(cl, off);
    if ((t & 63) == 0) cred[t >> 6] = cl;
    __syncthreads();
    if (t == 0)
        unsafeAtomicAdd(&ws[WS_COMMIT], (cred[0] + cred[1]) + (cred[2] + cred[3]));
}

// ------------------------------------------------- stats: esum + counts
__global__ __launch_bounds__(256) void vq_stats(
    const float* __restrict__ input, const int* __restrict__ ws_ids,
    float* __restrict__ ws) {
    __shared__ float es[4 * 520];
    __shared__ float cnt_s[DICT];

    int t = threadIdx.x;
    int bc = blockIdx.x;
    int b = bc >> 4, cg = bc & 15;

    #pragma unroll
    for (int i = t; i < 4 * 520; i += 256) es[i] = 0.f;
    if (cg == 0)
        for (int i = t; i < DICT; i += 256) cnt_s[i] = 0.f;

    const int* idg = ws_ids + b * HW;
    int4 idv[4];
    #pragma unroll
    for (int it = 0; it < 4; ++it)
        idv[it] = *(const int4*)(idg + (t + it * 256) * 4);
    __syncthreads();

    #pragma unroll
    for (int chl = 0; chl < 4; ++chl) {
        const float* xg = input + (size_t)b * (EMB * HW) + (size_t)(cg * 4 + chl) * HW;
        float* esr = es + chl * 520;
        #pragma unroll
        for (int it = 0; it < 4; ++it) {
            v4f x = *(const v4f*)(xg + (t + it * 256) * 4);
            atomicAdd(&esr[idv[it].x], x.x);
            atomicAdd(&esr[idv[it].y], x.y);
            atomicAdd(&esr[idv[it].z], x.z);
            atomicAdd(&esr[idv[it].w], x.w);
        }
    }
    if (cg == 0) {
        #pragma unroll
        for (int it = 0; it < 4; ++it) {
            atomicAdd(&cnt_s[idv[it].x], 1.f);
            atomicAdd(&cnt_s[idv[it].y], 1.f);
            atomicAdd(&cnt_s[idv[it].z], 1.f);
            atomicAdd(&cnt_s[idv[it].w], 1.f);
        }
    }
    __syncthreads();

    #pragma unroll
    for (int i = t; i < 4 * DICT; i += 256) {
        int chl = i >> 9, j = i & 511;
        float v = es[chl * 520 + j];
        if (v != 0.f)
            unsafeAtomicAdd(&ws[WS_ESUM + (cg * 4 + chl) * DICT + j], v);
    }
    if (cg == 0)
        for (int i = t; i < DICT; i += 256) {
            float c = cnt_s[i];
            if (c != 0.f) unsafeAtomicAdd(&ws[WS_COUNTS + i], c);
        }
}

// ---------------------------------------------------------------- finalize 1
__global__ __launch_bounds__(512) void vq_fin1(
    const float* __restrict__ cluster_size, float* __restrict__ ws,
    float* __restrict__ out_cs, float* __restrict__ out_loss) {
    __shared__ float red[DICT];
    int d = threadIdx.x;
    float ncs = cluster_size[d] * MOM + ws[WS_COUNTS + d] * OMOM;
    out_cs[d] = ncs;
    red[d] = ncs;
    __syncthreads();
    #pragma unroll
    for (int off = 256; off > 0; off >>= 1) {
        if (d < off) red[d] += red[d + off];
        __syncthreads();
    }
    if (d == 0) {
        ws[WS_N] = red[0];
        out_loss[0] = ws[WS_COMMIT] * (1.0f / (float)((size_t)NPTS * EMB));
    }
}

// ---------------------------------------------------------------- finalize 2
__global__ __launch_bounds__(256) void vq_fin2(
    const float* __restrict__ embed_avg, const float* __restrict__ cluster_size,
    const float* __restrict__ ws, float* __restrict__ out_embed,
    float* __restrict__ out_avg) {
    int idx = blockIdx.x * 256 + threadIdx.x;  // idx = ch*512 + d
    int ch = idx >> 9, d = idx & 511;
    float avg = embed_avg[idx] * MOM + ws[WS_ESUM + idx] * OMOM;
    out_avg[idx] = avg;
    float n = ws[WS_N];
    float ncs = cluster_size[d] * MOM + ws[WS_COUNTS + d] * OMOM;
    float cs = n * (ncs + EPSV) / (n + (float)DICT * EPSV);
    out_embed[d * EMB + ch] = avg / cs;
}

extern "C" void kernel_launch(void* const* d_in, const int* in_sizes, int n_in,
                              void* d_out, int out_size, void* d_ws, size_t ws_size,
                              hipStream_t stream) {
    const float* input        = (const float*)d_in[0];
    const float* embed        = (const float*)d_in[1];
    const float* cluster_size = (const float*)d_in[2];
    const float* embed_avg    = (const float*)d_in[3];

    float* out   = (float*)d_out;
    float* q     = out;                         // 8388608
    float* loss  = out + 8388608;               // 1
    float* ids   = out + 8388609;               // 131072
    float* oemb  = out + 8519681;               // 32768
    float* ocs   = out + 8552449;               // 512
    float* oavg  = out + 8552961;               // 32768
    float* ws    = (float*)d_ws;

    hipMemsetAsync(d_ws, 0, (size_t)WS_ZERO_FLOATS * sizeof(float), stream);
    vq_prep  <<<4, 256, 0, stream>>>(embed, (uint*)(ws + WS_EHG),
                                     (uint*)(ws + WS_ELG), ws + WS_EE);
    vq_argmax<<<1024, 256, 0, stream>>>(input, (const uint*)(ws + WS_EHG),
                                        (const uint*)(ws + WS_ELG), ws + WS_EE,
                                        embed, q, ids, (int*)(ws + WS_IDS), ws);
    vq_stats <<<512, 256, 0, stream>>>(input, (const int*)(ws + WS_IDS), ws);
    vq_fin1  <<<1, 512, 0, stream>>>(cluster_size, ws, ocs, loss);
    vq_fin2  <<<128, 256, 0, stream>>>(embed_avg, cluster_size, ws, oemb, oavg);
}

// Round 9
// 142.193 us; speedup vs baseline: 1.7471x; 1.0540x over previous
//
#include <hip/hip_runtime.h>

#define EMB 64
#define DICT 512
#define HW 4096              // 64*64
#define NPTS (32 * HW)       // 131072
#define MOM 0.99f
#define OMOM 0.01f
#define EPSV 1e-5f

typedef float v4f __attribute__((ext_vector_type(4)));
typedef unsigned int uint;
typedef uint uint4v __attribute__((ext_vector_type(4)));
typedef short short8 __attribute__((ext_vector_type(8)));
typedef __bf16 bf16x8 __attribute__((ext_vector_type(8)));
typedef float f32x4 __attribute__((ext_vector_type(4)));

// ws layout (dword offsets)
#define WS_COMMIT 0
#define WS_COUNTS 64                      // 512
#define WS_ESUM   1024                    // 64*512
#define WS_ZERO_FLOATS 33792              // zero [0, 33792) each call
#define WS_EE     33792                   // 512 (fp32 ||e||^2)
#define WS_N      34304                   // 1
#define WS_EHG    34320                   // 4 tiles * 4160 = 16640 (packed bf16-hi E)
#define WS_ELG    50960                   // 16640 (packed bf16-lo E)
#define WS_IDS    67600                   // 131072 ints (natural pixel order)

#define PS 520      // plane stride in dwords: 130 rows x 4 dwords
#define TB 4160     // tile blob: 8 planes (kh*4+g)

__device__ __forceinline__ uint bf16rne(float x) {
    uint u = __float_as_uint(x);
    return (u + 0x7fffu + ((u >> 16) & 1u)) >> 16;
}

__device__ __forceinline__ bf16x8 ldfrag(const uint* s, int idx) {
    return __builtin_bit_cast(bf16x8, *(const short8*)(s + idx));
}

// ------------------------------------------------- prep: pack E hi/lo + ||e||^2
__global__ __launch_bounds__(256) void vq_prep(const float* __restrict__ embed,
                                               uint* __restrict__ ehg,
                                               uint* __restrict__ elg,
                                               float* __restrict__ ee) {
    __shared__ float pn[256];
    int t = threadIdx.x;
    int tt = blockIdx.x;
    int jl = t & 127;
    int j = tt * 128 + jl;
    int half = t >> 7;
    float nrm = 0.f;
    #pragma unroll
    for (int i = 0; i < 16; ++i) {
        int c2 = half * 16 + i;
        float x0 = embed[j * 64 + 2 * c2];
        float x1 = embed[j * 64 + 2 * c2 + 1];
        nrm = fmaf(x0, x0, nrm);
        nrm = fmaf(x1, x1, nrm);
        uint h0 = bf16rne(x0), h1 = bf16rne(x1);
        float hf0 = __uint_as_float(h0 << 16), hf1 = __uint_as_float(h1 << 16);
        uint l0 = bf16rne(x0 - hf0), l1 = bf16rne(x1 - hf1);
        int plane = (c2 >> 4) * 4 + ((c2 >> 2) & 3);
        int idx = tt * TB + plane * PS + jl * 4 + (c2 & 3);
        ehg[idx] = h0 | (h1 << 16);
        elg[idx] = l0 | (l1 << 16);
    }
    pn[t] = nrm;
    __syncthreads();
    if (t < 128) ee[tt * 128 + t] = pn[t] + pn[t + 128];
}

// ------------------------------------------------- MFMA argmax + exact rescore
// block: 128 points, 4 waves. B-fragments loaded DIRECTLY from L2-resident
// packed E (no LDS staging, no inner barriers) -> 4 blocks/CU occupancy.
__global__ __launch_bounds__(256, 4) void vq_argmax(
    const float* __restrict__ input, const uint* __restrict__ ehg,
    const uint* __restrict__ elg, const float* __restrict__ ee,
    const float* __restrict__ embed, float* __restrict__ out_q,
    float* __restrict__ out_ids, int* __restrict__ ws_ids,
    float* __restrict__ ws) {
    __shared__ uint sXh[TB], sXl[TB];
    __shared__ float sEE[512];
    __shared__ int sCand[256];
    __shared__ float sRes[256];
    __shared__ float cred[4];

    int t = threadIdx.x;
    int blk = blockIdx.x;
    int b = blk >> 5, h2 = blk & 31;

    // ---- stage X as packed hi/lo bf16 planes (conflict-free writes) ----
    {
        int p = t & 127;
        const float* xg = input + (size_t)b * (EMB * HW) + h2 * 128 + p;
        #pragma unroll
        for (int i = 0; i < 16; ++i) {
            int c2 = (t >> 7) * 16 + i;
            float x0 = xg[(size_t)(2 * c2) * HW];
            float x1 = xg[(size_t)(2 * c2 + 1) * HW];
            uint h0 = bf16rne(x0), h1 = bf16rne(x1);
            float hf0 = __uint_as_float(h0 << 16), hf1 = __uint_as_float(h1 << 16);
            uint l0 = bf16rne(x0 - hf0), l1 = bf16rne(x1 - hf1);
            int plane = (c2 >> 4) * 4 + ((c2 >> 2) & 3);
            int idx = plane * PS + p * 4 + (c2 & 3);
            sXh[idx] = h0 | (h1 << 16);
            sXl[idx] = l0 | (l1 << 16);
        }
        sEE[t] = ee[t];
        sEE[t + 256] = ee[t + 256];
    }
    __syncthreads();

    int l = t & 63, wv = t >> 6;
    int g = l >> 4, col = l & 15;

    // A fragments (X) — constant across all 4 code-tiles
    bf16x8 Ah[2][2], Al[2][2];     // [mt][kh]
    #pragma unroll
    for (int mt = 0; mt < 2; ++mt)
        #pragma unroll
        for (int kh = 0; kh < 2; ++kh) {
            int row = wv * 32 + mt * 16 + col;
            int idx = (kh * 4 + g) * PS + row * 4;
            Ah[mt][kh] = ldfrag(sXh, idx);
            Al[mt][kh] = ldfrag(sXl, idx);
        }

    // per-lane top-2 per (mt, r) slot
    float tb1[2][4], tb2[2][4];
    int ti1[2][4], ti2[2][4];
    #pragma unroll
    for (int mt = 0; mt < 2; ++mt)
        #pragma unroll
        for (int r = 0; r < 4; ++r) {
            tb1[mt][r] = -3.0e38f; tb2[mt][r] = -3.0e38f;
            ti1[mt][r] = 0; ti2[mt][r] = 0;
        }

    for (int jt = 0; jt < 4; ++jt) {
        const uint* eh = ehg + jt * TB;
        const uint* el = elg + jt * TB;
        #pragma unroll
        for (int nt = 0; nt < 8; ++nt) {
            int i0 = (0 * 4 + g) * PS + (nt * 16 + col) * 4;
            int i1x = (1 * 4 + g) * PS + (nt * 16 + col) * 4;
            bf16x8 Bh0 = ldfrag(eh, i0), Bl0 = ldfrag(el, i0);
            bf16x8 Bh1 = ldfrag(eh, i1x), Bl1 = ldfrag(el, i1x);
            float e2 = -0.5f * sEE[jt * 128 + nt * 16 + col];
            f32x4 acc0 = {e2, e2, e2, e2};
            f32x4 acc1 = acc0;
            acc0 = __builtin_amdgcn_mfma_f32_16x16x32_bf16(Ah[0][0], Bh0, acc0, 0, 0, 0);
            acc1 = __builtin_amdgcn_mfma_f32_16x16x32_bf16(Ah[1][0], Bh0, acc1, 0, 0, 0);
            acc0 = __builtin_amdgcn_mfma_f32_16x16x32_bf16(Ah[0][0], Bl0, acc0, 0, 0, 0);
            acc1 = __builtin_amdgcn_mfma_f32_16x16x32_bf16(Ah[1][0], Bl0, acc1, 0, 0, 0);
            acc0 = __builtin_amdgcn_mfma_f32_16x16x32_bf16(Al[0][0], Bh0, acc0, 0, 0, 0);
            acc1 = __builtin_amdgcn_mfma_f32_16x16x32_bf16(Al[1][0], Bh0, acc1, 0, 0, 0);
            acc0 = __builtin_amdgcn_mfma_f32_16x16x32_bf16(Ah[0][1], Bh1, acc0, 0, 0, 0);
            acc1 = __builtin_amdgcn_mfma_f32_16x16x32_bf16(Ah[1][1], Bh1, acc1, 0, 0, 0);
            acc0 = __builtin_amdgcn_mfma_f32_16x16x32_bf16(Ah[0][1], Bl1, acc0, 0, 0, 0);
            acc1 = __builtin_amdgcn_mfma_f32_16x16x32_bf16(Ah[1][1], Bl1, acc1, 0, 0, 0);
            acc0 = __builtin_amdgcn_mfma_f32_16x16x32_bf16(Al[0][1], Bh1, acc0, 0, 0, 0);
            acc1 = __builtin_amdgcn_mfma_f32_16x16x32_bf16(Al[1][1], Bh1, acc1, 0, 0, 0);
            // running top-2 folded in (codes ascending -> first-index tie-break)
            int jc = jt * 128 + nt * 16 + col;
            #pragma unroll
            for (int r = 0; r < 4; ++r) {
                float s0 = acc0[r];
                if (s0 > tb1[0][r]) {
                    tb2[0][r] = tb1[0][r]; ti2[0][r] = ti1[0][r];
                    tb1[0][r] = s0; ti1[0][r] = jc;
                } else if (s0 > tb2[0][r]) {
                    tb2[0][r] = s0; ti2[0][r] = jc;
                }
                float s1 = acc1[r];
                if (s1 > tb1[1][r]) {
                    tb2[1][r] = tb1[1][r]; ti2[1][r] = ti1[1][r];
                    tb1[1][r] = s1; ti1[1][r] = jc;
                } else if (s1 > tb2[1][r]) {
                    tb2[1][r] = s1; ti2[1][r] = jc;
                }
            }
        }
    }

    // 16-lane top-2 merge per point; lane col==0 publishes candidates
    #pragma unroll
    for (int mt = 0; mt < 2; ++mt)
        #pragma unroll
        for (int r = 0; r < 4; ++r) {
            float a1 = tb1[mt][r], a2 = tb2[mt][r];
            int j1 = ti1[mt][r], j2 = ti2[mt][r];
            #pragma unroll
            for (int off = 8; off > 0; off >>= 1) {
                float c1 = __shfl_xor(a1, off, 16); int k1 = __shfl_xor(j1, off, 16);
                float c2v = __shfl_xor(a2, off, 16); int k2 = __shfl_xor(j2, off, 16);
                bool af = (a1 > c1) || (a1 == c1 && j1 < k1);
                float n1 = af ? a1 : c1; int nj1 = af ? j1 : k1;
                float lx = af ? c1 : a1; int lj = af ? k1 : j1;   // loser of tops
                float wx = af ? a2 : c2v; int wj = af ? j2 : k2;  // winner's 2nd
                bool wf = (wx > lx) || (wx == lx && wj < lj);
                a1 = n1; j1 = nj1;
                a2 = wf ? wx : lx; j2 = wf ? wj : lj;
            }
            if (col == 0) {
                int p = wv * 32 + mt * 16 + g * 4 + r;
                sCand[p * 2] = j1;
                sCand[p * 2 + 1] = j2;
            }
        }
    __syncthreads();

    // ---- exact fp32 rescore of both candidates (2 threads per point) ----
    int p = t & 127, wc = t >> 7;
    int c = sCand[p * 2 + wc];
    const v4f* erow = (const v4f*)(embed + c * 64);
    float dot = 0.f;
    #pragma unroll
    for (int plane = 0; plane < 8; ++plane) {
        uint4v xh = *(const uint4v*)&sXh[plane * PS + p * 4];
        uint4v xl = *(const uint4v*)&sXl[plane * PS + p * 4];
        v4f e0 = erow[plane * 2];
        v4f e1 = erow[plane * 2 + 1];
        #pragma unroll
        for (int v = 0; v < 4; ++v) {
            float xe = __uint_as_float(xh[v] << 16) + __uint_as_float(xl[v] << 16);
            float xo = __uint_as_float(xh[v] & 0xffff0000u) + __uint_as_float(xl[v] & 0xffff0000u);
            float ev_ = (v < 2) ? e0[2 * (v & 1)] : e1[2 * (v & 1)];
            float ov_ = (v < 2) ? e0[2 * (v & 1) + 1] : e1[2 * (v & 1) + 1];
            dot = fmaf(xe, ev_, dot);
            dot = fmaf(xo, ov_, dot);
        }
    }
    float sx = fmaf(2.f, dot, -sEE[c]);
    sRes[t] = sx;
    __syncthreads();
    float so = sRes[t ^ 128];
    int co = sCand[p * 2 + (1 - wc)];
    bool win = (sx > so) || (sx == so && c < co);

    // winner: ids + quantized + commit contribution
    float cl = 0.f;
    if (win) {
        int h = (h2 << 1) + (p >> 6), w = p & 63;
        ws_ids[b * HW + h2 * 128 + p] = c;                 // natural order
        out_ids[b * HW + w * 64 + h] = (float)c;           // (b,w,h) quirk
        float* qg = out_q + (size_t)b * (EMB * HW) + h2 * 128 + p;
        #pragma unroll
        for (int plane = 0; plane < 8; ++plane) {
            uint4v xh = *(const uint4v*)&sXh[plane * PS + p * 4];
            uint4v xl = *(const uint4v*)&sXl[plane * PS + p * 4];
            v4f e0 = erow[plane * 2];
            v4f e1 = erow[plane * 2 + 1];
            #pragma unroll
            for (int v = 0; v < 4; ++v) {
                float xe = __uint_as_float(xh[v] << 16) + __uint_as_float(xl[v] << 16);
                float xo = __uint_as_float(xh[v] & 0xffff0000u) + __uint_as_float(xl[v] & 0xffff0000u);
                float ev_ = (v < 2) ? e0[2 * (v & 1)] : e1[2 * (v & 1)];
                float ov_ = (v < 2) ? e0[2 * (v & 1) + 1] : e1[2 * (v & 1) + 1];
                int ch = plane * 8 + 2 * v;
                qg[(size_t)ch * HW] = ev_;
                qg[(size_t)(ch + 1) * HW] = ov_;
                float d0 = xe - ev_, d1 = xo - ov_;
                cl = fmaf(d0, d0, cl);
                cl = fmaf(d1, d1, cl);
            }
        }
    }
    #pragma unroll
    for (int off = 32; off > 0; off >>= 1) cl += __shfl_down(cl, off);
    if ((t & 63) == 0) cred[t >> 6] = cl;
    __syncthreads();
    if (t == 0)
        unsafeAtomicAdd(&ws[WS_COMMIT], (cred[0] + cred[1]) + (cred[2] + cred[3]));
}

// ------------------------------------------------- stats: esum + counts
__global__ __launch_bounds__(256) void vq_stats(
    const float* __restrict__ input, const int* __restrict__ ws_ids,
    float* __restrict__ ws) {
    __shared__ float es[4 * 520];
    __shared__ float cnt_s[DICT];

    int t = threadIdx.x;
    int bc = blockIdx.x;
    int b = bc >> 4, cg = bc & 15;

    #pragma unroll
    for (int i = t; i < 4 * 520; i += 256) es[i] = 0.f;
    if (cg == 0)
        for (int i = t; i < DICT; i += 256) cnt_s[i] = 0.f;

    const int* idg = ws_ids + b * HW;
    int4 idv[4];
    #pragma unroll
    for (int it = 0; it < 4; ++it)
        idv[it] = *(const int4*)(idg + (t + it * 256) * 4);
    __syncthreads();

    #pragma unroll
    for (int chl = 0; chl < 4; ++chl) {
        const float* xg = input + (size_t)b * (EMB * HW) + (size_t)(cg * 4 + chl) * HW;
        float* esr = es + chl * 520;
        #pragma unroll
        for (int it = 0; it < 4; ++it) {
            v4f x = *(const v4f*)(xg + (t + it * 256) * 4);
            atomicAdd(&esr[idv[it].x], x.x);
            atomicAdd(&esr[idv[it].y], x.y);
            atomicAdd(&esr[idv[it].z], x.z);
            atomicAdd(&esr[idv[it].w], x.w);
        }
    }
    if (cg == 0) {
        #pragma unroll
        for (int it = 0; it < 4; ++it) {
            atomicAdd(&cnt_s[idv[it].x], 1.f);
            atomicAdd(&cnt_s[idv[it].y], 1.f);
            atomicAdd(&cnt_s[idv[it].z], 1.f);
            atomicAdd(&cnt_s[idv[it].w], 1.f);
        }
    }
    __syncthreads();

    #pragma unroll
    for (int i = t; i < 4 * DICT; i += 256) {
        int chl = i >> 9, j = i & 511;
        float v = es[chl * 520 + j];
        if (v != 0.f)
            unsafeAtomicAdd(&ws[WS_ESUM + (cg * 4 + chl) * DICT + j], v);
    }
    if (cg == 0)
        for (int i = t; i < DICT; i += 256) {
            float c = cnt_s[i];
            if (c != 0.f) unsafeAtomicAdd(&ws[WS_COUNTS + i], c);
        }
}

// ---------------------------------------------------------------- finalize 1
__global__ __launch_bounds__(512) void vq_fin1(
    const float* __restrict__ cluster_size, float* __restrict__ ws,
    float* __restrict__ out_cs, float* __restrict__ out_loss) {
    __shared__ float red[DICT];
    int d = threadIdx.x;
    float ncs = cluster_size[d] * MOM + ws[WS_COUNTS + d] * OMOM;
    out_cs[d] = ncs;
    red[d] = ncs;
    __syncthreads();
    #pragma unroll
    for (int off = 256; off > 0; off >>= 1) {
        if (d < off) red[d] += red[d + off];
        __syncthreads();
    }
    if (d == 0) {
        ws[WS_N] = red[0];
        out_loss[0] = ws[WS_COMMIT] * (1.0f / (float)((size_t)NPTS * EMB));
    }
}

// ---------------------------------------------------------------- finalize 2
__global__ __launch_bounds__(256) void vq_fin2(
    const float* __restrict__ embed_avg, const float* __restrict__ cluster_size,
    const float* __restrict__ ws, float* __restrict__ out_embed,
    float* __restrict__ out_avg) {
    int idx = blockIdx.x * 256 + threadIdx.x;  // idx = ch*512 + d
    int ch = idx >> 9, d = idx & 511;
    float avg = embed_avg[idx] * MOM + ws[WS_ESUM + idx] * OMOM;
    out_avg[idx] = avg;
    float n = ws[WS_N];
    float ncs = cluster_size[d] * MOM + ws[WS_COUNTS + d] * OMOM;
    float cs = n * (ncs + EPSV) / (n + (float)DICT * EPSV);
    out_embed[d * EMB + ch] = avg / cs;
}

extern "C" void kernel_launch(void* const* d_in, const int* in_sizes, int n_in,
                              void* d_out, int out_size, void* d_ws, size_t ws_size,
                              hipStream_t stream) {
    const float* input        = (const float*)d_in[0];
    const float* embed        = (const float*)d_in[1];
    const float* cluster_size = (const float*)d_in[2];
    const float* embed_avg    = (const float*)d_in[3];

    float* out   = (float*)d_out;
    float* q     = out;                         // 8388608
    float* loss  = out + 8388608;               // 1
    float* ids   = out + 8388609;               // 131072
    float* oemb  = out + 8519681;               // 32768
    float* ocs   = out + 8552449;               // 512
    float* oavg  = out + 8552961;               // 32768
    float* ws    = (float*)d_ws;

    hipMemsetAsync(d_ws, 0, (size_t)WS_ZERO_FLOATS * sizeof(float), stream);
    vq_prep  <<<4, 256, 0, stream>>>(embed, (uint*)(ws + WS_EHG),
                                     (uint*)(ws + WS_ELG), ws + WS_EE);
    vq_argmax<<<1024, 256, 0, stream>>>(input, (const uint*)(ws + WS_EHG),
                                        (const uint*)(ws + WS_ELG), ws + WS_EE,
                                        embed, q, ids, (int*)(ws + WS_IDS), ws);
    vq_stats <<<512, 256, 0, stream>>>(input, (const int*)(ws + WS_IDS), ws);
    vq_fin1  <<<1, 512, 0, stream>>>(cluster_size, ws, ocs, loss);
    vq_fin2  <<<128, 256, 0, stream>>>(embed_avg, cluster_size, ws, oemb, oavg);
}